// Round 2
// baseline (371.041 us; speedup 1.0000x reference)
//
#include <hip/hip_runtime.h>
#include <hip/hip_bf16.h>

typedef __hip_bfloat16 bf16;

typedef __bf16 bf16v8 __attribute__((ext_vector_type(8)));
typedef short  s16v8  __attribute__((ext_vector_type(8)));
typedef float  f32v4  __attribute__((ext_vector_type(4)));

#define NBLK  256      // edge-pass blocks (power of 2)
#define NBLKL 8        // log2(NBLK)

__device__ __forceinline__ float bf2f(unsigned short u) {
    return __uint_as_float(((unsigned)u) << 16);
}
__device__ __forceinline__ float bflo(unsigned v) {
    return __uint_as_float(v << 16);
}
__device__ __forceinline__ float bfhi(unsigned v) {
    return __uint_as_float(v & 0xFFFF0000u);
}
__device__ __forceinline__ float ldx(const void* p, size_t i, bool f32) {
    return f32 ? ((const float*)p)[i] : bf2f(((const unsigned short*)p)[i]);
}
__device__ __forceinline__ unsigned short f2bfbits(float f) {
    union { bf16 h; unsigned short u; } cv;
    cv.h = __float2bfloat16(f);
    return cv.u;
}
__device__ __forceinline__ float wave_sum(float v) {
    #pragma unroll
    for (int o = 32; o > 0; o >>= 1) v += __shfl_xor(v, o);
    return v;
}
// logical (bucket-major) -> physical (block-major) index for the hist matrix
__device__ __forceinline__ int physidx(int l, int NBtot) {
    return (l & (NBLK - 1)) * NBtot + (l >> NBLKL);
}

// ---------------------------------------------------------------------------
// dtype detector (f32 vs bf16 inputs)
// ---------------------------------------------------------------------------
__global__ void detect_kernel(const unsigned* __restrict__ x, int nwords,
                              int* __restrict__ flag)
{
    __shared__ int cnt;
    if (threadIdx.x == 0) cnt = 0;
    __syncthreads();
    int c = 0;
    for (int i = threadIdx.x; i < nwords; i += blockDim.x) {
        unsigned e = (x[i] >> 23) & 0xFFu;
        if (e >= 100u && e <= 150u) c++;
    }
    atomicAdd(&cnt, c);
    __syncthreads();
    if (threadIdx.x == 0) flag[0] = (2 * cnt > nwords) ? 1 : 0;
}

// ---------------------------------------------------------------------------
// Relation set
// ---------------------------------------------------------------------------
struct RelSet {
    const int *src0, *dst0, *src1, *dst1, *src2, *dst2, *src3, *dst3;
    int off1, off2, off3, off4;
    int nd0, nd1, nd2, nd3;
};

__device__ __forceinline__ void pick(const RelSet& rs, int e, int& r,
                                     const int*& s, const int*& d, int& le)
{
    if (e < rs.off1)      { r = 0; s = rs.src0; d = rs.dst0; le = e; }
    else if (e < rs.off2) { r = 1; s = rs.src1; d = rs.dst1; le = e - rs.off1; }
    else if (e < rs.off3) { r = 2; s = rs.src2; d = rs.dst2; le = e - rs.off2; }
    else                  { r = 3; s = rs.src3; d = rs.dst3; le = e - rs.off3; }
}
__device__ __forceinline__ int ndst_of(const RelSet& rs, int r)
{
    return r == 0 ? rs.nd0 : r == 1 ? rs.nd1 : r == 2 ? rs.nd2 : rs.nd3;
}

// ---------------------------------------------------------------------------
// Pass 1: per-(block,bucket) LDS histogram -> hist[block*NBtot + bucket]
// ---------------------------------------------------------------------------
__global__ __launch_bounds__(1024) void pass1_kernel(
    RelSet rs, int* __restrict__ hist, int NBr)
{
    extern __shared__ int lh[];
    const int NBtot = 4 * NBr;
    for (int i = threadIdx.x; i < NBtot; i += 1024) lh[i] = 0;
    __syncthreads();
    for (int e = blockIdx.x * 1024 + threadIdx.x; e < rs.off4; e += NBLK * 1024) {
        int r, le; const int *s, *d;
        pick(rs, e, r, s, d, le);
        atomicAdd(&lh[r * NBr + (d[le] >> 7)], 1);
    }
    __syncthreads();
    for (int i = threadIdx.x; i < NBtot; i += 1024)
        hist[blockIdx.x * NBtot + i] = lh[i];
}

// ---------------------------------------------------------------------------
// Exclusive scan over the hist matrix in LOGICAL (bucket-major) order.
// ---------------------------------------------------------------------------
__global__ __launch_bounds__(1024) void gscan_a_kernel(
    int* __restrict__ buf, int n, int NBtot, int* __restrict__ partials)
{
    __shared__ int sh[1024];
    const int t = threadIdx.x;
    const int base = blockIdx.x * 4096 + t * 4;
    int p0 = 0, p1 = 0, p2 = 0, p3 = 0;
    int v0 = 0, v1 = 0, v2 = 0, v3 = 0;
    if (base < n)     { p0 = physidx(base,     NBtot); v0 = buf[p0]; }
    if (base + 1 < n) { p1 = physidx(base + 1, NBtot); v1 = buf[p1]; }
    if (base + 2 < n) { p2 = physidx(base + 2, NBtot); v2 = buf[p2]; }
    if (base + 3 < n) { p3 = physidx(base + 3, NBtot); v3 = buf[p3]; }
    const int tsum = v0 + v1 + v2 + v3;
    sh[t] = tsum;
    __syncthreads();
    for (int o = 1; o < 1024; o <<= 1) {
        int u = (t >= o) ? sh[t - o] : 0;
        __syncthreads();
        sh[t] += u;
        __syncthreads();
    }
    const int texcl = sh[t] - tsum;
    if (base < n)     buf[p0] = texcl;
    if (base + 1 < n) buf[p1] = texcl + v0;
    if (base + 2 < n) buf[p2] = texcl + v0 + v1;
    if (base + 3 < n) buf[p3] = texcl + v0 + v1 + v2;
    if (t == 1023) partials[blockIdx.x] = sh[t];
}

__global__ __launch_bounds__(1024) void gscan_b_kernel(int* __restrict__ partials,
                                                       int nb)
{
    __shared__ int sh[1024];
    const int t = threadIdx.x;
    int v = (t < nb) ? partials[t] : 0;
    sh[t] = v;
    __syncthreads();
    for (int o = 1; o < 1024; o <<= 1) {
        int u = (t >= o) ? sh[t - o] : 0;
        __syncthreads();
        sh[t] += u;
        __syncthreads();
    }
    if (t < nb) partials[t] = sh[t] - v;   // exclusive
}

__global__ void gscan_c_kernel(int* __restrict__ buf,
                               const int* __restrict__ partials, int n, int NBtot)
{
    int l = blockIdx.x * blockDim.x + threadIdx.x;
    if (l < n) buf[physidx(l, NBtot)] += partials[l >> 12];
}

// ---------------------------------------------------------------------------
// Scatter pass: append (src | dfine<<16) into block-private bucket ranges.
// ---------------------------------------------------------------------------
__global__ __launch_bounds__(1024) void scatter_kernel(
    RelSet rs, const int* __restrict__ O, unsigned* __restrict__ temp, int NBr)
{
    extern __shared__ int cur[];
    const int NBtot = 4 * NBr;
    for (int i = threadIdx.x; i < NBtot; i += 1024)
        cur[i] = O[blockIdx.x * NBtot + i];
    __syncthreads();
    for (int e = blockIdx.x * 1024 + threadIdx.x; e < rs.off4; e += NBLK * 1024) {
        int r, le; const int *s, *d;
        pick(rs, e, r, s, d, le);
        int dd = d[le];
        int b = r * NBr + (dd >> 7);
        int pos = atomicAdd(&cur[b], 1);
        temp[pos] = (unsigned)s[le] | ((unsigned)(dd & 127) << 16);
    }
}

// ---------------------------------------------------------------------------
// Fill: one block per bucket; rowptr + edge placement, all block-local.
// ---------------------------------------------------------------------------
__global__ __launch_bounds__(256) void fillb_kernel(
    RelSet rs, const int* __restrict__ O, const unsigned* __restrict__ temp,
    int* __restrict__ rowptr4, unsigned short* __restrict__ esrc4,
    int NBr, int NP, int EP, int TE)
{
    __shared__ int cnt[128];
    __shared__ int cur[128];
    const int b = blockIdx.x;
    const int NBtot = 4 * NBr;
    const int r = b / NBr;
    const int bloc = b - r * NBr;
    const int dbase = bloc << 7;
    const int nd = ndst_of(rs, r);
    const int bstart = O[b];
    const int bend   = (b + 1 < NBtot) ? O[b + 1] : TE;
    const int relstart = O[r * NBr];
    const int relend   = (r + 1 < 4) ? O[(r + 1) * NBr] : TE;
    const int t = threadIdx.x;

    if (t < 128) cnt[t] = 0;
    __syncthreads();
    for (int i = bstart + t; i < bend; i += 256)
        atomicAdd(&cnt[temp[i] >> 16], 1);
    __syncthreads();
    const int orig = (t < 128) ? cnt[t] : 0;
    for (int o = 1; o < 128; o <<= 1) {
        int add = 0;
        if (t < 128 && t >= o) add = cnt[t - o];
        __syncthreads();
        if (t < 128) cnt[t] += add;
        __syncthreads();
    }
    const int bucket_base = bstart - relstart;
    if (t < 128) {
        const int excl = cnt[t] - orig;
        cur[t] = bucket_base + excl;
        const int d = dbase + t;
        if (d < nd) rowptr4[r * (NP + 1) + d] = bucket_base + excl;
    }
    if (t == 0 && bloc == NBr - 1)
        rowptr4[r * (NP + 1) + nd] = relend - relstart;
    __syncthreads();
    unsigned short* es = esrc4 + (size_t)r * EP;
    for (int i = bstart + t; i < bend; i += 256) {
        unsigned u = temp[i];
        int pos = atomicAdd(&cur[u >> 16], 1);
        es[pos] = (unsigned short)(u & 0xFFFFu);
    }
}

// ---------------------------------------------------------------------------
// pack4: pre-transpose 4 weight matrices into global B-frag order (bf16 bits):
// Wp[((kt*4+ct)*64 + quad*16+n)*8 + j] = bf16(W[kt*32+quad*8+j][ct*16+n])
// ---------------------------------------------------------------------------
__device__ __forceinline__ void pack_one(const void* W, unsigned short* Wp,
                                         int i, bool f32)
{
    int k = i >> 6, c = i & 63;
    int kt = k >> 5, q = (k >> 3) & 3, j = k & 7;
    int ct = c >> 4, n = c & 15;
    Wp[(((kt * 4 + ct) * 64) + q * 16 + n) * 8 + j] = f2bfbits(ldx(W, i, f32));
}

__global__ __launch_bounds__(256) void pack4_kernel(
    const void* __restrict__ W0, const void* __restrict__ W1,
    const void* __restrict__ W2, const void* __restrict__ W3,
    unsigned short* __restrict__ P0, unsigned short* __restrict__ P1,
    unsigned short* __restrict__ P2, unsigned short* __restrict__ P3,
    const int* __restrict__ flag)
{
    const bool f32 = (flag[0] != 0);
    int i = blockIdx.x * 256 + threadIdx.x;
    if (i < 8192)       pack_one(W0, P0, i, f32);
    else if (i < 16384) pack_one(W1, P1, i - 8192, f32);
    else if (i < 24576) pack_one(W2, P2, i - 16384, f32);
    else if (i < 28672) pack_one(W3, P3, i - 24576, f32);
}

// ---------------------------------------------------------------------------
// wvec2: wv1 = W1 @ a1, wv2 = W2 @ a2 (both K=128)
// ---------------------------------------------------------------------------
__global__ void wvec2_kernel(const void* __restrict__ W1, const void* __restrict__ a1,
                             const void* __restrict__ W2, const void* __restrict__ a2,
                             float* __restrict__ wv1, float* __restrict__ wv2,
                             const int* __restrict__ flag)
{
    const bool f32 = (flag[0] != 0);
    const int t = threadIdx.x;
    const void* W = (t < 128) ? W1 : W2;
    const void* a = (t < 128) ? a1 : a2;
    const int k = t & 127;
    float s = 0.f;
    for (int c = 0; c < 64; ++c) s += ldx(W, (size_t)k * 64 + c, f32) * ldx(a, c, f32);
    ((t < 128) ? wv1 : wv2)[k] = s;
}

// ---------------------------------------------------------------------------
// MFMA projection: B-frags loaded straight from packed global W (no LDS).
// ---------------------------------------------------------------------------
struct ProjArg {
    const void* X; const unsigned short* Wp; const void* a1; const void* a2;
    const float* wvx;
    bf16* H; float* al1; float* al2; float* alx;
    int N;
};

template <int K>
__device__ __forceinline__ void proj_body(const ProjArg& P, bool f32,
                                          int bid, int nblocks)
{
    constexpr int NKT = K / 32;
    const int tid = threadIdx.x;
    const int wave = tid >> 6, lane = tid & 63;
    const int quad = lane >> 4, n = lane & 15;

    // B fragments: 16 coalesced 16B global loads (L2-hot), conflict-free
    s16v8 Bf[NKT][4];
    #pragma unroll
    for (int kt = 0; kt < NKT; ++kt)
        #pragma unroll
        for (int ct = 0; ct < 4; ++ct)
            Bf[kt][ct] = *(const s16v8*)&P.Wp[((kt * 4 + ct) * 64 + lane) * 8];

    float a1v[4], a2v[4];
    #pragma unroll
    for (int ct = 0; ct < 4; ++ct) {
        a1v[ct] = P.a1 ? ldx(P.a1, ct * 16 + n, f32) : 0.f;
        a2v[ct] = P.a2 ? ldx(P.a2, ct * 16 + n, f32) : 0.f;
    }
    float wv[NKT][8];
    if (P.wvx) {
        #pragma unroll
        for (int kt = 0; kt < NKT; ++kt)
            #pragma unroll
            for (int j = 0; j < 8; ++j)
                wv[kt][j] = P.wvx[kt * 32 + quad * 8 + j];
    }

    const int tiles = (P.N + 15) / 16;
    for (int tb = bid * 4 + wave; tb < tiles; tb += nblocks * 4) {
        const int r0 = tb * 16;
        const int arow = r0 + n;
        const int ars  = (arow < P.N) ? arow : 0;

        f32v4 acc[4];
        #pragma unroll
        for (int ct = 0; ct < 4; ++ct) acc[ct] = (f32v4){0.f, 0.f, 0.f, 0.f};
        float txd = 0.f;

        #pragma unroll
        for (int kt = 0; kt < NKT; ++kt) {
            s16v8 As;
            if (f32) {
                const float4* xp = (const float4*)P.X +
                    ((size_t)ars * K + kt * 32 + quad * 8) / 4;
                float4 x0 = xp[0], x1 = xp[1];
                As[0] = (short)f2bfbits(x0.x); As[1] = (short)f2bfbits(x0.y);
                As[2] = (short)f2bfbits(x0.z); As[3] = (short)f2bfbits(x0.w);
                As[4] = (short)f2bfbits(x1.x); As[5] = (short)f2bfbits(x1.y);
                As[6] = (short)f2bfbits(x1.z); As[7] = (short)f2bfbits(x1.w);
            } else {
                As = *(const s16v8*)((const unsigned short*)P.X +
                    (size_t)ars * K + kt * 32 + quad * 8);
            }
            if (P.wvx) {
                #pragma unroll
                for (int j = 0; j < 8; ++j)
                    txd = fmaf(bf2f((unsigned short)As[j]), wv[kt][j], txd);
            }
            bf16v8 Ab = __builtin_bit_cast(bf16v8, As);
            #pragma unroll
            for (int ct = 0; ct < 4; ++ct)
                acc[ct] = __builtin_amdgcn_mfma_f32_16x16x32_bf16(
                    Ab, __builtin_bit_cast(bf16v8, Bf[kt][ct]), acc[ct], 0, 0, 0);
        }

        if (P.alx) {
            txd += __shfl_xor(txd, 16);
            txd += __shfl_xor(txd, 32);
            if (lane < 16 && r0 + lane < P.N) P.alx[r0 + lane] = txd;
        }

        #pragma unroll
        for (int i = 0; i < 4; ++i) {
            const int r = r0 + quad * 4 + i;
            const bool rv = (r < P.N);
            if (rv && P.H) {
                #pragma unroll
                for (int ct = 0; ct < 4; ++ct)
                    P.H[(size_t)r * 64 + ct * 16 + n] = __float2bfloat16(acc[ct][i]);
            }
            if (P.al1) {
                float t = acc[0][i] * a1v[0] + acc[1][i] * a1v[1] +
                          acc[2][i] * a1v[2] + acc[3][i] * a1v[3];
                #pragma unroll
                for (int o = 1; o < 16; o <<= 1) t += __shfl_xor(t, o);
                if (rv && n == 0) P.al1[r] = t;
            }
            if (P.al2) {
                float t = acc[0][i] * a2v[0] + acc[1][i] * a2v[1] +
                          acc[2][i] * a2v[2] + acc[3][i] * a2v[3];
                #pragma unroll
                for (int o = 1; o < 16; o <<= 1) t += __shfl_xor(t, o);
                if (rv && n == 0) P.al2[r] = t;
            }
        }
    }
}

template <int KA, int KB, int KC>
__global__ __launch_bounds__(256) void proj3_kernel(ProjArg A, ProjArg B, ProjArg C,
                                                    int nA, int nB,
                                                    const int* __restrict__ flag)
{
    const bool f32 = (flag[0] != 0);
    const int bx = blockIdx.x;
    if (bx < nA)            proj_body<KA>(A, f32, bx, nA);
    else if (bx < nA + nB)  proj_body<KB>(B, f32, bx - nA, nB);
    else                    proj_body<KC>(C, f32, bx - nA - nB,
                                          gridDim.x - nA - nB);
}

template <int K>
__global__ __launch_bounds__(256) void proj1_kernel(ProjArg A,
                                                    const int* __restrict__ flag)
{
    proj_body<K>(A, flag[0] != 0, blockIdx.x, gridDim.x);
}

// ---------------------------------------------------------------------------
// Fused dual-relation softmax aggregation.
// Wave = 8 edge-groups x 8 channel-groups; each lane gathers 16B (8 bf16
// channels = one eighth of a 128B H row) per load. Inner loop covers a
// 16-edge window of BOTH relations per iteration -> 4 independent 16B
// gathers in flight per lane (MLP=4, matching the 4B-load variant) at
// 1/4 the VMEM instruction count and 1/2 the shfl count.
// ---------------------------------------------------------------------------
__global__ __launch_bounds__(256) void agg2_kernel(
    const int* __restrict__ rp1, const unsigned short* __restrict__ es1,
    const unsigned* __restrict__ HS1, const float* __restrict__ als1,
    const float* __restrict__ ald1,
    const int* __restrict__ rp2, const unsigned short* __restrict__ es2,
    const unsigned* __restrict__ HS2, const float* __restrict__ als2,
    const float* __restrict__ ald2,
    const void* __restrict__ b1, const void* __restrict__ b2,
    void* __restrict__ out, size_t out_off, int n, const int* __restrict__ flag)
{
    const int gw   = (blockIdx.x * blockDim.x + threadIdx.x) >> 6;
    const int lane = threadIdx.x & 63;
    if (gw >= n) return;
    const int eg = lane >> 3;     // edge group 0..7
    const int cg = lane & 7;      // channel group: u32 words cg*4 .. cg*4+3

    int p1 = rp1[gw], e1 = rp1[gw + 1];
    int p2 = rp2[gw], e2 = rp2[gw + 1];
    const float ad1 = ald1[gw], ad2 = ald2[gw];

    float acc1[8] = {0.f, 0.f, 0.f, 0.f, 0.f, 0.f, 0.f, 0.f};
    float acc2[8] = {0.f, 0.f, 0.f, 0.f, 0.f, 0.f, 0.f, 0.f};
    float den1 = 0.f, den2 = 0.f;

    while (p1 < e1 || p2 < e2) {
        int nn1 = e1 - p1; nn1 = nn1 < 0 ? 0 : (nn1 > 64 ? 64 : nn1);
        int nn2 = e2 - p2; nn2 = nn2 < 0 ? 0 : (nn2 > 64 ? 64 : nn2);
        int s1 = 0, s2 = 0; float w1 = 0.f, w2 = 0.f;
        if (lane < nn1) {
            s1 = es1[p1 + lane];
            float l = als1[s1] + ad1;
            l = (l > 0.f) ? l : 0.2f * l;
            w1 = __expf(l);
        }
        if (lane < nn2) {
            s2 = es2[p2 + lane];
            float l = als2[s2] + ad2;
            l = (l > 0.f) ? l : 0.2f * l;
            w2 = __expf(l);
        }
        den1 += w1; den2 += w2;

        const int jm = (nn1 > nn2) ? nn1 : nn2;
        for (int j = 0; j < jm; j += 16) {
            // 16-edge window, both relations: 4 independent 16B gathers.
            int   sA1 = __shfl(s1, j + eg),     sB1 = __shfl(s1, j + 8 + eg);
            float wA1 = __shfl(w1, j + eg),     wB1 = __shfl(w1, j + 8 + eg);
            int   sA2 = __shfl(s2, j + eg),     sB2 = __shfl(s2, j + 8 + eg);
            float wA2 = __shfl(w2, j + eg),     wB2 = __shfl(w2, j + 8 + eg);
            uint4 vA1 = *(const uint4*)&HS1[(size_t)sA1 * 32 + cg * 4];
            uint4 vB1 = *(const uint4*)&HS1[(size_t)sB1 * 32 + cg * 4];
            uint4 vA2 = *(const uint4*)&HS2[(size_t)sA2 * 32 + cg * 4];
            uint4 vB2 = *(const uint4*)&HS2[(size_t)sB2 * 32 + cg * 4];
            acc1[0] = fmaf(wA1, bflo(vA1.x), acc1[0]);
            acc1[1] = fmaf(wA1, bfhi(vA1.x), acc1[1]);
            acc1[2] = fmaf(wA1, bflo(vA1.y), acc1[2]);
            acc1[3] = fmaf(wA1, bfhi(vA1.y), acc1[3]);
            acc1[4] = fmaf(wA1, bflo(vA1.z), acc1[4]);
            acc1[5] = fmaf(wA1, bfhi(vA1.z), acc1[5]);
            acc1[6] = fmaf(wA1, bflo(vA1.w), acc1[6]);
            acc1[7] = fmaf(wA1, bfhi(vA1.w), acc1[7]);
            acc1[0] = fmaf(wB1, bflo(vB1.x), acc1[0]);
            acc1[1] = fmaf(wB1, bfhi(vB1.x), acc1[1]);
            acc1[2] = fmaf(wB1, bflo(vB1.y), acc1[2]);
            acc1[3] = fmaf(wB1, bfhi(vB1.y), acc1[3]);
            acc1[4] = fmaf(wB1, bflo(vB1.z), acc1[4]);
            acc1[5] = fmaf(wB1, bfhi(vB1.z), acc1[5]);
            acc1[6] = fmaf(wB1, bflo(vB1.w), acc1[6]);
            acc1[7] = fmaf(wB1, bfhi(vB1.w), acc1[7]);
            acc2[0] = fmaf(wA2, bflo(vA2.x), acc2[0]);
            acc2[1] = fmaf(wA2, bfhi(vA2.x), acc2[1]);
            acc2[2] = fmaf(wA2, bflo(vA2.y), acc2[2]);
            acc2[3] = fmaf(wA2, bfhi(vA2.y), acc2[3]);
            acc2[4] = fmaf(wA2, bflo(vA2.z), acc2[4]);
            acc2[5] = fmaf(wA2, bfhi(vA2.z), acc2[5]);
            acc2[6] = fmaf(wA2, bflo(vA2.w), acc2[6]);
            acc2[7] = fmaf(wA2, bfhi(vA2.w), acc2[7]);
            acc2[0] = fmaf(wB2, bflo(vB2.x), acc2[0]);
            acc2[1] = fmaf(wB2, bfhi(vB2.x), acc2[1]);
            acc2[2] = fmaf(wB2, bflo(vB2.y), acc2[2]);
            acc2[3] = fmaf(wB2, bfhi(vB2.y), acc2[3]);
            acc2[4] = fmaf(wB2, bflo(vB2.z), acc2[4]);
            acc2[5] = fmaf(wB2, bfhi(vB2.z), acc2[5]);
            acc2[6] = fmaf(wB2, bflo(vB2.w), acc2[6]);
            acc2[7] = fmaf(wB2, bfhi(vB2.w), acc2[7]);
        }
        p1 += nn1; p2 += nn2;
    }

    // reduce across the 8 edge groups (lanes differing in bits 3..5)
    #pragma unroll
    for (int o = 8; o < 64; o <<= 1) {
        #pragma unroll
        for (int k = 0; k < 8; ++k) {
            acc1[k] += __shfl_xor(acc1[k], o);
            acc2[k] += __shfl_xor(acc2[k], o);
        }
    }
    den1 = wave_sum(den1);
    den2 = wave_sum(den2);
    const float inv1 = 1.0f / (den1 + 1e-16f);
    const float inv2 = 1.0f / (den2 + 1e-16f);

    if (eg == 0) {
        const bool f32 = (flag[0] != 0);
        const int c0 = cg * 8;
        float v[8];
        #pragma unroll
        for (int k = 0; k < 8; ++k)
            v[k] = 0.5f * (acc1[k] * inv1 + acc2[k] * inv2 +
                           ldx(b1, c0 + k, f32) + ldx(b2, c0 + k, f32));
        if (f32) {
            float4* op = (float4*)((float*)out + out_off + (size_t)gw * 64 + c0);
            op[0] = make_float4(v[0], v[1], v[2], v[3]);
            op[1] = make_float4(v[4], v[5], v[6], v[7]);
        } else {
            uint4 pk;
            pk.x = (unsigned)f2bfbits(v[0]) | ((unsigned)f2bfbits(v[1]) << 16);
            pk.y = (unsigned)f2bfbits(v[2]) | ((unsigned)f2bfbits(v[3]) << 16);
            pk.z = (unsigned)f2bfbits(v[4]) | ((unsigned)f2bfbits(v[5]) << 16);
            pk.w = (unsigned)f2bfbits(v[6]) | ((unsigned)f2bfbits(v[7]) << 16);
            *(uint4*)((unsigned short*)out + out_off + (size_t)gw * 64 + c0) = pk;
        }
    }
}

// ---------------------------------------------------------------------------
extern "C" void kernel_launch(void* const* d_in, const int* in_sizes, int n_in,
                              void* d_out, int out_size, void* d_ws, size_t ws_size,
                              hipStream_t stream)
{
    const void* x_t = d_in[0];
    const void* x_d = d_in[1];
    const int* ei_tt = (const int*)d_in[2];
    const int* ei_dt = (const int*)d_in[3];
    const int* ei_dd = (const int*)d_in[4];
    const int* ei_td = (const int*)d_in[5];
    const void* W_tt     = d_in[6];
    const void* att_tt_s = d_in[7];
    const void* att_tt_d = d_in[8];
    const void* b_tt     = d_in[9];
    const void* W_dt_src = d_in[10];
    const void* W_dt_dst = d_in[11];
    const void* att_dt_s = d_in[12];
    const void* att_dt_d = d_in[13];
    const void* b_dt     = d_in[14];
    const void* W_dd     = d_in[15];
    const void* att_dd_s = d_in[16];
    const void* att_dd_d = d_in[17];
    const void* b_dd     = d_in[18];
    const void* W_td_src = d_in[19];
    const void* W_td_dst = d_in[20];
    const void* att_td_s = d_in[21];
    const void* att_td_d = d_in[22];
    const void* b_td     = d_in[23];

    const int NT = in_sizes[0] / 128;
    const int ND = in_sizes[1] / 128;
    const int Ett = in_sizes[2] / 2, Edt = in_sizes[3] / 2,
              Edd = in_sizes[4] / 2, Etd = in_sizes[5] / 2;
    const int NMAX = (NT > ND) ? NT : ND;
    int EMAX = Ett;
    if (Edt > EMAX) EMAX = Edt;
    if (Edd > EMAX) EMAX = Edd;
    if (Etd > EMAX) EMAX = Etd;
    const int TE = Ett + Edt + Edd + Etd;

    const int NBr  = (NMAX + 127) >> 7;      // buckets per relation
    const int NBtot = 4 * NBr;
    const int HM = NBtot * NBLK;             // histogram matrix size

    // ---- workspace ----
    char* wptr = (char*)d_ws;
    auto alloc = [&](size_t bytes) -> void* {
        void* p = (void*)wptr;
        wptr += (bytes + 255) & ~(size_t)255;
        return p;
    };
    bf16*  h1      = (bf16*)alloc((size_t)NMAX * 64 * 2);
    bf16*  h2      = (bf16*)alloc((size_t)NMAX * 64 * 2);
    float* als[4]; float* ald[4];
    for (int r = 0; r < 4; ++r) {
        als[r] = (float*)alloc((size_t)NMAX * 4);
        ald[r] = (float*)alloc((size_t)NMAX * 4);
    }
    int*   hist    = (int*)alloc((size_t)HM * 4);
    int*   rowptr4 = (int*)alloc((size_t)4 * (NMAX + 1) * 4);
    unsigned short* esrc4 = (unsigned short*)alloc((size_t)4 * EMAX * 2);
    unsigned* temp = (unsigned*)alloc((size_t)TE * 4);
    int*   gpart   = (int*)alloc(1024 * 4);
    float* wvec_dt = (float*)alloc(128 * 4);
    float* wvec_td = (float*)alloc(128 * 4);
    unsigned short* wp_tt = (unsigned short*)alloc(8192 * 2);
    unsigned short* wp_dt = (unsigned short*)alloc(8192 * 2);
    unsigned short* wp_dd = (unsigned short*)alloc(8192 * 2);
    unsigned short* wp_td = (unsigned short*)alloc(4096 * 2);
    int*   flag    = (int*)alloc(256 * 4);
    bf16*  h3      = (bf16*)temp;   // temp dead after fillb; alias for dd's H

    RelSet rs;
    rs.src0 = ei_tt; rs.dst0 = ei_tt + Ett;
    rs.src1 = ei_dt; rs.dst1 = ei_dt + Edt;
    rs.src2 = ei_dd; rs.dst2 = ei_dd + Edd;
    rs.src3 = ei_td; rs.dst3 = ei_td + Etd;
    rs.off1 = Ett; rs.off2 = Ett + Edt; rs.off3 = Ett + Edt + Edd; rs.off4 = TE;
    rs.nd0 = NT; rs.nd1 = NT; rs.nd2 = ND; rs.nd3 = ND;

    detect_kernel<<<1, 256, 0, stream>>>((const unsigned*)x_t, 4096, flag);

    // ---- weight packing + wvecs (tiny) ----
    pack4_kernel<<<112, 256, 0, stream>>>(W_tt, W_dt_src, W_dd, W_td_src,
                                          wp_tt, wp_dt, wp_dd, wp_td, flag);
    wvec2_kernel<<<1, 256, 0, stream>>>(W_dt_dst, att_dt_d, W_td_dst, att_td_d,
                                        wvec_dt, wvec_td, flag);

    // ---- CSR build ----
    const size_t ldsB = (size_t)NBtot * 4;
    pass1_kernel<<<NBLK, 1024, ldsB, stream>>>(rs, hist, NBr);
    const int gnb = (HM + 4095) / 4096;
    gscan_a_kernel<<<gnb, 1024, 0, stream>>>(hist, HM, NBtot, gpart);
    gscan_b_kernel<<<1, 1024, 0, stream>>>(gpart, gnb);
    gscan_c_kernel<<<(HM + 255) / 256, 256, 0, stream>>>(hist, gpart, HM, NBtot);
    scatter_kernel<<<NBLK, 1024, ldsB, stream>>>(rs, hist, temp, NBr);
    fillb_kernel<<<NBtot, 256, 0, stream>>>(rs, hist, temp, rowptr4, esrc4,
                                            NBr, NMAX, EMAX, TE);

    // ---- projections tt -> h1, dt -> h2, dd -> h3 (temp alias) ----
    ProjArg Ptt{ x_t, wp_tt, att_tt_s, att_tt_d, wvec_dt,
                 h1, als[0], ald[0], ald[1], NT };
    ProjArg Pdt{ x_d, wp_dt, att_dt_s, nullptr, wvec_td,
                 h2, als[1], nullptr, ald[3], ND };
    ProjArg Pdd{ x_d, wp_dd, att_dd_s, att_dd_d, nullptr,
                 h3, als[2], ald[2], nullptr, ND };
    proj3_kernel<128, 128, 128><<<2304, 256, 0, stream>>>(Ptt, Pdt, Pdd,
                                                          768, 768, flag);

    // ---- target aggregate (tt rel0 + dt rel1) -> x_target_new ----
    agg2_kernel<<<(NT + 3) / 4, 256, 0, stream>>>(
        rowptr4 + 0 * (NMAX + 1), esrc4 + (size_t)0 * EMAX,
        (const unsigned*)h1, als[0], ald[0],
        rowptr4 + 1 * (NMAX + 1), esrc4 + (size_t)1 * EMAX,
        (const unsigned*)h2, als[1], ald[1],
        b_tt, b_dt, d_out, 0, NT, flag);

    // ---- td projection (reads x_target_new) -> h1 (reused) ----
    ProjArg Ptd{ d_out, wp_td, att_td_s, nullptr, nullptr,
                 h1, als[3], nullptr, nullptr, NT };
    proj1_kernel<64><<<1024, 256, 0, stream>>>(Ptd, flag);

    // ---- drug aggregate (dd rel2 + td rel3) -> x_drug_new ----
    agg2_kernel<<<(ND + 3) / 4, 256, 0, stream>>>(
        rowptr4 + 2 * (NMAX + 1), esrc4 + (size_t)2 * EMAX,
        (const unsigned*)h3, als[2], ald[2],
        rowptr4 + 3 * (NMAX + 1), esrc4 + (size_t)3 * EMAX,
        (const unsigned*)h1, als[3], ald[3],
        b_dd, b_td, d_out, (size_t)NT * 64, ND, flag);
}

// Round 3
// 344.773 us; speedup vs baseline: 1.0762x; 1.0762x over previous
//
#include <hip/hip_runtime.h>
#include <hip/hip_bf16.h>

typedef __hip_bfloat16 bf16;

typedef __bf16 bf16v8 __attribute__((ext_vector_type(8)));
typedef short  s16v8  __attribute__((ext_vector_type(8)));
typedef float  f32v4  __attribute__((ext_vector_type(4)));

#define NBLK  256      // edge-pass blocks (power of 2)
#define NBLKL 8        // log2(NBLK)

__device__ __forceinline__ float bf2f(unsigned short u) {
    return __uint_as_float(((unsigned)u) << 16);
}
__device__ __forceinline__ float bflo(unsigned v) {
    return __uint_as_float(v << 16);
}
__device__ __forceinline__ float bfhi(unsigned v) {
    return __uint_as_float(v & 0xFFFF0000u);
}
__device__ __forceinline__ float ldx(const void* p, size_t i, bool f32) {
    return f32 ? ((const float*)p)[i] : bf2f(((const unsigned short*)p)[i]);
}
__device__ __forceinline__ unsigned short f2bfbits(float f) {
    union { bf16 h; unsigned short u; } cv;
    cv.h = __float2bfloat16(f);
    return cv.u;
}
__device__ __forceinline__ float wave_sum(float v) {
    #pragma unroll
    for (int o = 32; o > 0; o >>= 1) v += __shfl_xor(v, o);
    return v;
}
// logical (bucket-major) -> physical (block-major) index for the hist matrix
__device__ __forceinline__ int physidx(int l, int NBtot) {
    return (l & (NBLK - 1)) * NBtot + (l >> NBLKL);
}

// ---------------------------------------------------------------------------
// dtype detector (f32 vs bf16 inputs)
// ---------------------------------------------------------------------------
__global__ void detect_kernel(const unsigned* __restrict__ x, int nwords,
                              int* __restrict__ flag)
{
    __shared__ int cnt;
    if (threadIdx.x == 0) cnt = 0;
    __syncthreads();
    int c = 0;
    for (int i = threadIdx.x; i < nwords; i += blockDim.x) {
        unsigned e = (x[i] >> 23) & 0xFFu;
        if (e >= 100u && e <= 150u) c++;
    }
    atomicAdd(&cnt, c);
    __syncthreads();
    if (threadIdx.x == 0) flag[0] = (2 * cnt > nwords) ? 1 : 0;
}

// ---------------------------------------------------------------------------
// Relation set
// ---------------------------------------------------------------------------
struct RelSet {
    const int *src0, *dst0, *src1, *dst1, *src2, *dst2, *src3, *dst3;
    int off1, off2, off3, off4;
    int nd0, nd1, nd2, nd3;
};

__device__ __forceinline__ void pick(const RelSet& rs, int e, int& r,
                                     const int*& s, const int*& d, int& le)
{
    if (e < rs.off1)      { r = 0; s = rs.src0; d = rs.dst0; le = e; }
    else if (e < rs.off2) { r = 1; s = rs.src1; d = rs.dst1; le = e - rs.off1; }
    else if (e < rs.off3) { r = 2; s = rs.src2; d = rs.dst2; le = e - rs.off2; }
    else                  { r = 3; s = rs.src3; d = rs.dst3; le = e - rs.off3; }
}
__device__ __forceinline__ int ndst_of(const RelSet& rs, int r)
{
    return r == 0 ? rs.nd0 : r == 1 ? rs.nd1 : r == 2 ? rs.nd2 : rs.nd3;
}

// ---------------------------------------------------------------------------
// Pass 1: per-(block,bucket) LDS histogram -> hist[block*NBtot + bucket]
// ---------------------------------------------------------------------------
__global__ __launch_bounds__(1024) void pass1_kernel(
    RelSet rs, int* __restrict__ hist, int NBr)
{
    extern __shared__ int lh[];
    const int NBtot = 4 * NBr;
    for (int i = threadIdx.x; i < NBtot; i += 1024) lh[i] = 0;
    __syncthreads();
    for (int e = blockIdx.x * 1024 + threadIdx.x; e < rs.off4; e += NBLK * 1024) {
        int r, le; const int *s, *d;
        pick(rs, e, r, s, d, le);
        atomicAdd(&lh[r * NBr + (d[le] >> 7)], 1);
    }
    __syncthreads();
    for (int i = threadIdx.x; i < NBtot; i += 1024)
        hist[blockIdx.x * NBtot + i] = lh[i];
}

// ---------------------------------------------------------------------------
// Exclusive scan over the hist matrix in LOGICAL (bucket-major) order.
// ---------------------------------------------------------------------------
__global__ __launch_bounds__(1024) void gscan_a_kernel(
    int* __restrict__ buf, int n, int NBtot, int* __restrict__ partials)
{
    __shared__ int sh[1024];
    const int t = threadIdx.x;
    const int base = blockIdx.x * 4096 + t * 4;
    int p0 = 0, p1 = 0, p2 = 0, p3 = 0;
    int v0 = 0, v1 = 0, v2 = 0, v3 = 0;
    if (base < n)     { p0 = physidx(base,     NBtot); v0 = buf[p0]; }
    if (base + 1 < n) { p1 = physidx(base + 1, NBtot); v1 = buf[p1]; }
    if (base + 2 < n) { p2 = physidx(base + 2, NBtot); v2 = buf[p2]; }
    if (base + 3 < n) { p3 = physidx(base + 3, NBtot); v3 = buf[p3]; }
    const int tsum = v0 + v1 + v2 + v3;
    sh[t] = tsum;
    __syncthreads();
    for (int o = 1; o < 1024; o <<= 1) {
        int u = (t >= o) ? sh[t - o] : 0;
        __syncthreads();
        sh[t] += u;
        __syncthreads();
    }
    const int texcl = sh[t] - tsum;
    if (base < n)     buf[p0] = texcl;
    if (base + 1 < n) buf[p1] = texcl + v0;
    if (base + 2 < n) buf[p2] = texcl + v0 + v1;
    if (base + 3 < n) buf[p3] = texcl + v0 + v1 + v2;
    if (t == 1023) partials[blockIdx.x] = sh[t];
}

__global__ __launch_bounds__(1024) void gscan_b_kernel(int* __restrict__ partials,
                                                       int nb)
{
    __shared__ int sh[1024];
    const int t = threadIdx.x;
    int v = (t < nb) ? partials[t] : 0;
    sh[t] = v;
    __syncthreads();
    for (int o = 1; o < 1024; o <<= 1) {
        int u = (t >= o) ? sh[t - o] : 0;
        __syncthreads();
        sh[t] += u;
        __syncthreads();
    }
    if (t < nb) partials[t] = sh[t] - v;   // exclusive
}

__global__ void gscan_c_kernel(int* __restrict__ buf,
                               const int* __restrict__ partials, int n, int NBtot)
{
    int l = blockIdx.x * blockDim.x + threadIdx.x;
    if (l < n) buf[physidx(l, NBtot)] += partials[l >> 12];
}

// ---------------------------------------------------------------------------
// Scatter pass: append (src | dfine<<16) into block-private bucket ranges.
// ---------------------------------------------------------------------------
__global__ __launch_bounds__(1024) void scatter_kernel(
    RelSet rs, const int* __restrict__ O, unsigned* __restrict__ temp, int NBr)
{
    extern __shared__ int cur[];
    const int NBtot = 4 * NBr;
    for (int i = threadIdx.x; i < NBtot; i += 1024)
        cur[i] = O[blockIdx.x * NBtot + i];
    __syncthreads();
    for (int e = blockIdx.x * 1024 + threadIdx.x; e < rs.off4; e += NBLK * 1024) {
        int r, le; const int *s, *d;
        pick(rs, e, r, s, d, le);
        int dd = d[le];
        int b = r * NBr + (dd >> 7);
        int pos = atomicAdd(&cur[b], 1);
        temp[pos] = (unsigned)s[le] | ((unsigned)(dd & 127) << 16);
    }
}

// ---------------------------------------------------------------------------
// Fill: one block per bucket; rowptr + edge placement, all block-local.
// ---------------------------------------------------------------------------
__global__ __launch_bounds__(256) void fillb_kernel(
    RelSet rs, const int* __restrict__ O, const unsigned* __restrict__ temp,
    int* __restrict__ rowptr4, unsigned short* __restrict__ esrc4,
    int NBr, int NP, int EP, int TE)
{
    __shared__ int cnt[128];
    __shared__ int cur[128];
    const int b = blockIdx.x;
    const int NBtot = 4 * NBr;
    const int r = b / NBr;
    const int bloc = b - r * NBr;
    const int dbase = bloc << 7;
    const int nd = ndst_of(rs, r);
    const int bstart = O[b];
    const int bend   = (b + 1 < NBtot) ? O[b + 1] : TE;
    const int relstart = O[r * NBr];
    const int relend   = (r + 1 < 4) ? O[(r + 1) * NBr] : TE;
    const int t = threadIdx.x;

    if (t < 128) cnt[t] = 0;
    __syncthreads();
    for (int i = bstart + t; i < bend; i += 256)
        atomicAdd(&cnt[temp[i] >> 16], 1);
    __syncthreads();
    const int orig = (t < 128) ? cnt[t] : 0;
    for (int o = 1; o < 128; o <<= 1) {
        int add = 0;
        if (t < 128 && t >= o) add = cnt[t - o];
        __syncthreads();
        if (t < 128) cnt[t] += add;
        __syncthreads();
    }
    const int bucket_base = bstart - relstart;
    if (t < 128) {
        const int excl = cnt[t] - orig;
        cur[t] = bucket_base + excl;
        const int d = dbase + t;
        if (d < nd) rowptr4[r * (NP + 1) + d] = bucket_base + excl;
    }
    if (t == 0 && bloc == NBr - 1)
        rowptr4[r * (NP + 1) + nd] = relend - relstart;
    __syncthreads();
    unsigned short* es = esrc4 + (size_t)r * EP;
    for (int i = bstart + t; i < bend; i += 256) {
        unsigned u = temp[i];
        int pos = atomicAdd(&cur[u >> 16], 1);
        es[pos] = (unsigned short)(u & 0xFFFFu);
    }
}

// ---------------------------------------------------------------------------
// pack4: pre-transpose 4 weight matrices into global B-frag order (bf16 bits):
// Wp[((kt*4+ct)*64 + quad*16+n)*8 + j] = bf16(W[kt*32+quad*8+j][ct*16+n])
// ---------------------------------------------------------------------------
__device__ __forceinline__ void pack_one(const void* W, unsigned short* Wp,
                                         int i, bool f32)
{
    int k = i >> 6, c = i & 63;
    int kt = k >> 5, q = (k >> 3) & 3, j = k & 7;
    int ct = c >> 4, n = c & 15;
    Wp[(((kt * 4 + ct) * 64) + q * 16 + n) * 8 + j] = f2bfbits(ldx(W, i, f32));
}

__global__ __launch_bounds__(256) void pack4_kernel(
    const void* __restrict__ W0, const void* __restrict__ W1,
    const void* __restrict__ W2, const void* __restrict__ W3,
    unsigned short* __restrict__ P0, unsigned short* __restrict__ P1,
    unsigned short* __restrict__ P2, unsigned short* __restrict__ P3,
    const int* __restrict__ flag)
{
    const bool f32 = (flag[0] != 0);
    int i = blockIdx.x * 256 + threadIdx.x;
    if (i < 8192)       pack_one(W0, P0, i, f32);
    else if (i < 16384) pack_one(W1, P1, i - 8192, f32);
    else if (i < 24576) pack_one(W2, P2, i - 16384, f32);
    else if (i < 28672) pack_one(W3, P3, i - 24576, f32);
}

// ---------------------------------------------------------------------------
// wvec2: wv1 = W1 @ a1, wv2 = W2 @ a2 (both K=128)
// ---------------------------------------------------------------------------
__global__ void wvec2_kernel(const void* __restrict__ W1, const void* __restrict__ a1,
                             const void* __restrict__ W2, const void* __restrict__ a2,
                             float* __restrict__ wv1, float* __restrict__ wv2,
                             const int* __restrict__ flag)
{
    const bool f32 = (flag[0] != 0);
    const int t = threadIdx.x;
    const void* W = (t < 128) ? W1 : W2;
    const void* a = (t < 128) ? a1 : a2;
    const int k = t & 127;
    float s = 0.f;
    for (int c = 0; c < 64; ++c) s += ldx(W, (size_t)k * 64 + c, f32) * ldx(a, c, f32);
    ((t < 128) ? wv1 : wv2)[k] = s;
}

// ---------------------------------------------------------------------------
// MFMA projection: B-frags loaded straight from packed global W (no LDS).
// ---------------------------------------------------------------------------
struct ProjArg {
    const void* X; const unsigned short* Wp; const void* a1; const void* a2;
    const float* wvx;
    bf16* H; float* al1; float* al2; float* alx;
    int N;
};

template <int K>
__device__ __forceinline__ void proj_body(const ProjArg& P, bool f32,
                                          int bid, int nblocks)
{
    constexpr int NKT = K / 32;
    const int tid = threadIdx.x;
    const int wave = tid >> 6, lane = tid & 63;
    const int quad = lane >> 4, n = lane & 15;

    // B fragments: 16 coalesced 16B global loads (L2-hot), conflict-free
    s16v8 Bf[NKT][4];
    #pragma unroll
    for (int kt = 0; kt < NKT; ++kt)
        #pragma unroll
        for (int ct = 0; ct < 4; ++ct)
            Bf[kt][ct] = *(const s16v8*)&P.Wp[((kt * 4 + ct) * 64 + lane) * 8];

    float a1v[4], a2v[4];
    #pragma unroll
    for (int ct = 0; ct < 4; ++ct) {
        a1v[ct] = P.a1 ? ldx(P.a1, ct * 16 + n, f32) : 0.f;
        a2v[ct] = P.a2 ? ldx(P.a2, ct * 16 + n, f32) : 0.f;
    }
    float wv[NKT][8];
    if (P.wvx) {
        #pragma unroll
        for (int kt = 0; kt < NKT; ++kt)
            #pragma unroll
            for (int j = 0; j < 8; ++j)
                wv[kt][j] = P.wvx[kt * 32 + quad * 8 + j];
    }

    const int tiles = (P.N + 15) / 16;
    for (int tb = bid * 4 + wave; tb < tiles; tb += nblocks * 4) {
        const int r0 = tb * 16;
        const int arow = r0 + n;
        const int ars  = (arow < P.N) ? arow : 0;

        f32v4 acc[4];
        #pragma unroll
        for (int ct = 0; ct < 4; ++ct) acc[ct] = (f32v4){0.f, 0.f, 0.f, 0.f};
        float txd = 0.f;

        #pragma unroll
        for (int kt = 0; kt < NKT; ++kt) {
            s16v8 As;
            if (f32) {
                const float4* xp = (const float4*)P.X +
                    ((size_t)ars * K + kt * 32 + quad * 8) / 4;
                float4 x0 = xp[0], x1 = xp[1];
                As[0] = (short)f2bfbits(x0.x); As[1] = (short)f2bfbits(x0.y);
                As[2] = (short)f2bfbits(x0.z); As[3] = (short)f2bfbits(x0.w);
                As[4] = (short)f2bfbits(x1.x); As[5] = (short)f2bfbits(x1.y);
                As[6] = (short)f2bfbits(x1.z); As[7] = (short)f2bfbits(x1.w);
            } else {
                As = *(const s16v8*)((const unsigned short*)P.X +
                    (size_t)ars * K + kt * 32 + quad * 8);
            }
            if (P.wvx) {
                #pragma unroll
                for (int j = 0; j < 8; ++j)
                    txd = fmaf(bf2f((unsigned short)As[j]), wv[kt][j], txd);
            }
            bf16v8 Ab = __builtin_bit_cast(bf16v8, As);
            #pragma unroll
            for (int ct = 0; ct < 4; ++ct)
                acc[ct] = __builtin_amdgcn_mfma_f32_16x16x32_bf16(
                    Ab, __builtin_bit_cast(bf16v8, Bf[kt][ct]), acc[ct], 0, 0, 0);
        }

        if (P.alx) {
            txd += __shfl_xor(txd, 16);
            txd += __shfl_xor(txd, 32);
            if (lane < 16 && r0 + lane < P.N) P.alx[r0 + lane] = txd;
        }

        #pragma unroll
        for (int i = 0; i < 4; ++i) {
            const int r = r0 + quad * 4 + i;
            const bool rv = (r < P.N);
            if (rv && P.H) {
                #pragma unroll
                for (int ct = 0; ct < 4; ++ct)
                    P.H[(size_t)r * 64 + ct * 16 + n] = __float2bfloat16(acc[ct][i]);
            }
            if (P.al1) {
                float t = acc[0][i] * a1v[0] + acc[1][i] * a1v[1] +
                          acc[2][i] * a1v[2] + acc[3][i] * a1v[3];
                #pragma unroll
                for (int o = 1; o < 16; o <<= 1) t += __shfl_xor(t, o);
                if (rv && n == 0) P.al1[r] = t;
            }
            if (P.al2) {
                float t = acc[0][i] * a2v[0] + acc[1][i] * a2v[1] +
                          acc[2][i] * a2v[2] + acc[3][i] * a2v[3];
                #pragma unroll
                for (int o = 1; o < 16; o <<= 1) t += __shfl_xor(t, o);
                if (rv && n == 0) P.al2[r] = t;
            }
        }
    }
}

template <int KA, int KB, int KC>
__global__ __launch_bounds__(256) void proj3_kernel(ProjArg A, ProjArg B, ProjArg C,
                                                    int nA, int nB,
                                                    const int* __restrict__ flag)
{
    const bool f32 = (flag[0] != 0);
    const int bx = blockIdx.x;
    if (bx < nA)            proj_body<KA>(A, f32, bx, nA);
    else if (bx < nA + nB)  proj_body<KB>(B, f32, bx - nA, nB);
    else                    proj_body<KC>(C, f32, bx - nA - nB,
                                          gridDim.x - nA - nB);
}

template <int K>
__global__ __launch_bounds__(256) void proj1_kernel(ProjArg A,
                                                    const int* __restrict__ flag)
{
    proj_body<K>(A, flag[0] != 0, blockIdx.x, gridDim.x);
}

// ---------------------------------------------------------------------------
// Fused dual-relation softmax aggregation, 2 channels/lane (round-0 proven
// structure). Single change vs round 0: #pragma unroll 4 on the j-loop so
// the compiler hoists shfl address calc and keeps ~16 independent gather
// loads in flight before the first waitcnt (addresses depend only on s/w
// computed before the loop).
// ---------------------------------------------------------------------------
__global__ __launch_bounds__(256) void agg2_kernel(
    const int* __restrict__ rp1, const unsigned short* __restrict__ es1,
    const unsigned* __restrict__ HS1, const float* __restrict__ als1,
    const float* __restrict__ ald1,
    const int* __restrict__ rp2, const unsigned short* __restrict__ es2,
    const unsigned* __restrict__ HS2, const float* __restrict__ als2,
    const float* __restrict__ ald2,
    const void* __restrict__ b1, const void* __restrict__ b2,
    void* __restrict__ out, size_t out_off, int n, const int* __restrict__ flag)
{
    const int gw   = (blockIdx.x * blockDim.x + threadIdx.x) >> 6;
    const int lane = threadIdx.x & 63;
    if (gw >= n) return;
    const int half = lane >> 5;      // 0: edge j, 1: edge j+1
    const int ch2  = lane & 31;      // channel pair (2*ch2, 2*ch2+1)

    int p1 = rp1[gw], e1 = rp1[gw + 1];
    int p2 = rp2[gw], e2 = rp2[gw + 1];
    const float ad1 = ald1[gw], ad2 = ald2[gw];

    float l1a = 0.f, h1a = 0.f, l1b = 0.f, h1b = 0.f, den1 = 0.f;
    float l2a = 0.f, h2a = 0.f, l2b = 0.f, h2b = 0.f, den2 = 0.f;

    while (p1 < e1 || p2 < e2) {
        int nn1 = e1 - p1; nn1 = nn1 < 0 ? 0 : (nn1 > 64 ? 64 : nn1);
        int nn2 = e2 - p2; nn2 = nn2 < 0 ? 0 : (nn2 > 64 ? 64 : nn2);
        int s1 = 0, s2 = 0; float w1 = 0.f, w2 = 0.f;
        if (lane < nn1) {
            s1 = es1[p1 + lane];
            float l = als1[s1] + ad1;
            l = (l > 0.f) ? l : 0.2f * l;
            w1 = __expf(l);
        }
        if (lane < nn2) {
            s2 = es2[p2 + lane];
            float l = als2[s2] + ad2;
            l = (l > 0.f) ? l : 0.2f * l;
            w2 = __expf(l);
        }
        den1 += w1; den2 += w2;

        const int jm = (nn1 > nn2) ? nn1 : nn2;
        #pragma unroll 4
        for (int j = 0; j < jm; j += 4) {
            int   sA1 = __shfl(s1, j + half), sB1 = __shfl(s1, j + 2 + half);
            float wA1 = __shfl(w1, j + half), wB1 = __shfl(w1, j + 2 + half);
            int   sA2 = __shfl(s2, j + half), sB2 = __shfl(s2, j + 2 + half);
            float wA2 = __shfl(w2, j + half), wB2 = __shfl(w2, j + 2 + half);
            unsigned vA1 = HS1[(size_t)sA1 * 32 + ch2];
            unsigned vB1 = HS1[(size_t)sB1 * 32 + ch2];
            unsigned vA2 = HS2[(size_t)sA2 * 32 + ch2];
            unsigned vB2 = HS2[(size_t)sB2 * 32 + ch2];
            l1a = fmaf(wA1, bflo(vA1), l1a); h1a = fmaf(wA1, bfhi(vA1), h1a);
            l1b = fmaf(wB1, bflo(vB1), l1b); h1b = fmaf(wB1, bfhi(vB1), h1b);
            l2a = fmaf(wA2, bflo(vA2), l2a); h2a = fmaf(wA2, bfhi(vA2), h2a);
            l2b = fmaf(wB2, bflo(vB2), l2b); h2b = fmaf(wB2, bfhi(vB2), h2b);
        }
        p1 += nn1; p2 += nn2;
    }

    float lo1 = l1a + l1b, hi1 = h1a + h1b;
    float lo2 = l2a + l2b, hi2 = h2a + h2b;
    lo1 += __shfl_xor(lo1, 32); hi1 += __shfl_xor(hi1, 32);
    lo2 += __shfl_xor(lo2, 32); hi2 += __shfl_xor(hi2, 32);
    den1 = wave_sum(den1);
    den2 = wave_sum(den2);
    const float inv1 = 1.0f / (den1 + 1e-16f);
    const float inv2 = 1.0f / (den2 + 1e-16f);

    if (half == 0) {
        const bool f32 = (flag[0] != 0);
        const int c0 = 2 * ch2;
        float vlo = 0.5f * (lo1 * inv1 + lo2 * inv2 +
                            ldx(b1, c0, f32) + ldx(b2, c0, f32));
        float vhi = 0.5f * (hi1 * inv1 + hi2 * inv2 +
                            ldx(b1, c0 + 1, f32) + ldx(b2, c0 + 1, f32));
        const size_t pairidx = (out_off >> 1) + (size_t)gw * 32 + ch2;
        if (f32) ((float2*)out)[pairidx] = make_float2(vlo, vhi);
        else {
            ushort2 u2 = make_ushort2(f2bfbits(vlo), f2bfbits(vhi));
            ((ushort2*)out)[pairidx] = u2;
        }
    }
}

// ---------------------------------------------------------------------------
extern "C" void kernel_launch(void* const* d_in, const int* in_sizes, int n_in,
                              void* d_out, int out_size, void* d_ws, size_t ws_size,
                              hipStream_t stream)
{
    const void* x_t = d_in[0];
    const void* x_d = d_in[1];
    const int* ei_tt = (const int*)d_in[2];
    const int* ei_dt = (const int*)d_in[3];
    const int* ei_dd = (const int*)d_in[4];
    const int* ei_td = (const int*)d_in[5];
    const void* W_tt     = d_in[6];
    const void* att_tt_s = d_in[7];
    const void* att_tt_d = d_in[8];
    const void* b_tt     = d_in[9];
    const void* W_dt_src = d_in[10];
    const void* W_dt_dst = d_in[11];
    const void* att_dt_s = d_in[12];
    const void* att_dt_d = d_in[13];
    const void* b_dt     = d_in[14];
    const void* W_dd     = d_in[15];
    const void* att_dd_s = d_in[16];
    const void* att_dd_d = d_in[17];
    const void* b_dd     = d_in[18];
    const void* W_td_src = d_in[19];
    const void* W_td_dst = d_in[20];
    const void* att_td_s = d_in[21];
    const void* att_td_d = d_in[22];
    const void* b_td     = d_in[23];

    const int NT = in_sizes[0] / 128;
    const int ND = in_sizes[1] / 128;
    const int Ett = in_sizes[2] / 2, Edt = in_sizes[3] / 2,
              Edd = in_sizes[4] / 2, Etd = in_sizes[5] / 2;
    const int NMAX = (NT > ND) ? NT : ND;
    int EMAX = Ett;
    if (Edt > EMAX) EMAX = Edt;
    if (Edd > EMAX) EMAX = Edd;
    if (Etd > EMAX) EMAX = Etd;
    const int TE = Ett + Edt + Edd + Etd;

    const int NBr  = (NMAX + 127) >> 7;      // buckets per relation
    const int NBtot = 4 * NBr;
    const int HM = NBtot * NBLK;             // histogram matrix size

    // ---- workspace ----
    char* wptr = (char*)d_ws;
    auto alloc = [&](size_t bytes) -> void* {
        void* p = (void*)wptr;
        wptr += (bytes + 255) & ~(size_t)255;
        return p;
    };
    bf16*  h1      = (bf16*)alloc((size_t)NMAX * 64 * 2);
    bf16*  h2      = (bf16*)alloc((size_t)NMAX * 64 * 2);
    float* als[4]; float* ald[4];
    for (int r = 0; r < 4; ++r) {
        als[r] = (float*)alloc((size_t)NMAX * 4);
        ald[r] = (float*)alloc((size_t)NMAX * 4);
    }
    int*   hist    = (int*)alloc((size_t)HM * 4);
    int*   rowptr4 = (int*)alloc((size_t)4 * (NMAX + 1) * 4);
    unsigned short* esrc4 = (unsigned short*)alloc((size_t)4 * EMAX * 2);
    unsigned* temp = (unsigned*)alloc((size_t)TE * 4);
    int*   gpart   = (int*)alloc(1024 * 4);
    float* wvec_dt = (float*)alloc(128 * 4);
    float* wvec_td = (float*)alloc(128 * 4);
    unsigned short* wp_tt = (unsigned short*)alloc(8192 * 2);
    unsigned short* wp_dt = (unsigned short*)alloc(8192 * 2);
    unsigned short* wp_dd = (unsigned short*)alloc(8192 * 2);
    unsigned short* wp_td = (unsigned short*)alloc(4096 * 2);
    int*   flag    = (int*)alloc(256 * 4);
    bf16*  h3      = (bf16*)temp;   // temp dead after fillb; alias for dd's H

    RelSet rs;
    rs.src0 = ei_tt; rs.dst0 = ei_tt + Ett;
    rs.src1 = ei_dt; rs.dst1 = ei_dt + Edt;
    rs.src2 = ei_dd; rs.dst2 = ei_dd + Edd;
    rs.src3 = ei_td; rs.dst3 = ei_td + Etd;
    rs.off1 = Ett; rs.off2 = Ett + Edt; rs.off3 = Ett + Edt + Edd; rs.off4 = TE;
    rs.nd0 = NT; rs.nd1 = NT; rs.nd2 = ND; rs.nd3 = ND;

    detect_kernel<<<1, 256, 0, stream>>>((const unsigned*)x_t, 4096, flag);

    // ---- weight packing + wvecs (tiny) ----
    pack4_kernel<<<112, 256, 0, stream>>>(W_tt, W_dt_src, W_dd, W_td_src,
                                          wp_tt, wp_dt, wp_dd, wp_td, flag);
    wvec2_kernel<<<1, 256, 0, stream>>>(W_dt_dst, att_dt_d, W_td_dst, att_td_d,
                                        wvec_dt, wvec_td, flag);

    // ---- CSR build ----
    const size_t ldsB = (size_t)NBtot * 4;
    pass1_kernel<<<NBLK, 1024, ldsB, stream>>>(rs, hist, NBr);
    const int gnb = (HM + 4095) / 4096;
    gscan_a_kernel<<<gnb, 1024, 0, stream>>>(hist, HM, NBtot, gpart);
    gscan_b_kernel<<<1, 1024, 0, stream>>>(gpart, gnb);
    gscan_c_kernel<<<(HM + 255) / 256, 256, 0, stream>>>(hist, gpart, HM, NBtot);
    scatter_kernel<<<NBLK, 1024, ldsB, stream>>>(rs, hist, temp, NBr);
    fillb_kernel<<<NBtot, 256, 0, stream>>>(rs, hist, temp, rowptr4, esrc4,
                                            NBr, NMAX, EMAX, TE);

    // ---- projections tt -> h1, dt -> h2, dd -> h3 (temp alias) ----
    ProjArg Ptt{ x_t, wp_tt, att_tt_s, att_tt_d, wvec_dt,
                 h1, als[0], ald[0], ald[1], NT };
    ProjArg Pdt{ x_d, wp_dt, att_dt_s, nullptr, wvec_td,
                 h2, als[1], nullptr, ald[3], ND };
    ProjArg Pdd{ x_d, wp_dd, att_dd_s, att_dd_d, nullptr,
                 h3, als[2], ald[2], nullptr, ND };
    proj3_kernel<128, 128, 128><<<2304, 256, 0, stream>>>(Ptt, Pdt, Pdd,
                                                          768, 768, flag);

    // ---- target aggregate (tt rel0 + dt rel1) -> x_target_new ----
    agg2_kernel<<<(NT + 3) / 4, 256, 0, stream>>>(
        rowptr4 + 0 * (NMAX + 1), esrc4 + (size_t)0 * EMAX,
        (const unsigned*)h1, als[0], ald[0],
        rowptr4 + 1 * (NMAX + 1), esrc4 + (size_t)1 * EMAX,
        (const unsigned*)h2, als[1], ald[1],
        b_tt, b_dt, d_out, 0, NT, flag);

    // ---- td projection (reads x_target_new) -> h1 (reused) ----
    ProjArg Ptd{ d_out, wp_td, att_td_s, nullptr, nullptr,
                 h1, als[3], nullptr, nullptr, NT };
    proj1_kernel<64><<<1024, 256, 0, stream>>>(Ptd, flag);

    // ---- drug aggregate (dd rel2 + td rel3) -> x_drug_new ----
    agg2_kernel<<<(ND + 3) / 4, 256, 0, stream>>>(
        rowptr4 + 2 * (NMAX + 1), esrc4 + (size_t)2 * EMAX,
        (const unsigned*)h3, als[2], ald[2],
        rowptr4 + 3 * (NMAX + 1), esrc4 + (size_t)3 * EMAX,
        (const unsigned*)h1, als[3], ald[3],
        b_dd, b_td, d_out, (size_t)NT * 64, ND, flag);
}

// Round 4
// 334.260 us; speedup vs baseline: 1.1100x; 1.0315x over previous
//
#include <hip/hip_runtime.h>
#include <hip/hip_bf16.h>

typedef __hip_bfloat16 bf16;

typedef __bf16 bf16v8 __attribute__((ext_vector_type(8)));
typedef short  s16v8  __attribute__((ext_vector_type(8)));
typedef float  f32v4  __attribute__((ext_vector_type(4)));

#define NBLK  256      // edge-pass blocks (power of 2)
#define NBLKL 8        // log2(NBLK)

__device__ __forceinline__ float bf2f(unsigned short u) {
    return __uint_as_float(((unsigned)u) << 16);
}
__device__ __forceinline__ float bflo(unsigned v) {
    return __uint_as_float(v << 16);
}
__device__ __forceinline__ float bfhi(unsigned v) {
    return __uint_as_float(v & 0xFFFF0000u);
}
__device__ __forceinline__ float ldx(const void* p, size_t i, bool f32) {
    return f32 ? ((const float*)p)[i] : bf2f(((const unsigned short*)p)[i]);
}
__device__ __forceinline__ unsigned short f2bfbits(float f) {
    union { bf16 h; unsigned short u; } cv;
    cv.h = __float2bfloat16(f);
    return cv.u;
}
__device__ __forceinline__ float wave_sum(float v) {
    #pragma unroll
    for (int o = 32; o > 0; o >>= 1) v += __shfl_xor(v, o);
    return v;
}
// logical (bucket-major) -> physical (block-major) index for the hist matrix
__device__ __forceinline__ int physidx(int l, int NBtot) {
    return (l & (NBLK - 1)) * NBtot + (l >> NBLKL);
}

// ---------------------------------------------------------------------------
// dtype detector (f32 vs bf16 inputs)
// ---------------------------------------------------------------------------
__global__ void detect_kernel(const unsigned* __restrict__ x, int nwords,
                              int* __restrict__ flag)
{
    __shared__ int cnt;
    if (threadIdx.x == 0) cnt = 0;
    __syncthreads();
    int c = 0;
    for (int i = threadIdx.x; i < nwords; i += blockDim.x) {
        unsigned e = (x[i] >> 23) & 0xFFu;
        if (e >= 100u && e <= 150u) c++;
    }
    atomicAdd(&cnt, c);
    __syncthreads();
    if (threadIdx.x == 0) flag[0] = (2 * cnt > nwords) ? 1 : 0;
}

// ---------------------------------------------------------------------------
// Relation set
// ---------------------------------------------------------------------------
struct RelSet {
    const int *src0, *dst0, *src1, *dst1, *src2, *dst2, *src3, *dst3;
    int off1, off2, off3, off4;
    int nd0, nd1, nd2, nd3;
};

__device__ __forceinline__ void pick(const RelSet& rs, int e, int& r,
                                     const int*& s, const int*& d, int& le)
{
    if (e < rs.off1)      { r = 0; s = rs.src0; d = rs.dst0; le = e; }
    else if (e < rs.off2) { r = 1; s = rs.src1; d = rs.dst1; le = e - rs.off1; }
    else if (e < rs.off3) { r = 2; s = rs.src2; d = rs.dst2; le = e - rs.off2; }
    else                  { r = 3; s = rs.src3; d = rs.dst3; le = e - rs.off3; }
}
__device__ __forceinline__ int ndst_of(const RelSet& rs, int r)
{
    return r == 0 ? rs.nd0 : r == 1 ? rs.nd1 : r == 2 ? rs.nd2 : rs.nd3;
}

// ---------------------------------------------------------------------------
// Pass 1: per-(block,bucket) LDS histogram -> hist[block*NBtot + bucket]
// ---------------------------------------------------------------------------
__global__ __launch_bounds__(1024) void pass1_kernel(
    RelSet rs, int* __restrict__ hist, int NBr)
{
    extern __shared__ int lh[];
    const int NBtot = 4 * NBr;
    for (int i = threadIdx.x; i < NBtot; i += 1024) lh[i] = 0;
    __syncthreads();
    for (int e = blockIdx.x * 1024 + threadIdx.x; e < rs.off4; e += NBLK * 1024) {
        int r, le; const int *s, *d;
        pick(rs, e, r, s, d, le);
        atomicAdd(&lh[r * NBr + (d[le] >> 7)], 1);
    }
    __syncthreads();
    for (int i = threadIdx.x; i < NBtot; i += 1024)
        hist[blockIdx.x * NBtot + i] = lh[i];
}

// ---------------------------------------------------------------------------
// Exclusive scan over the hist matrix in LOGICAL (bucket-major) order.
// ---------------------------------------------------------------------------
__global__ __launch_bounds__(1024) void gscan_a_kernel(
    int* __restrict__ buf, int n, int NBtot, int* __restrict__ partials)
{
    __shared__ int sh[1024];
    const int t = threadIdx.x;
    const int base = blockIdx.x * 4096 + t * 4;
    int p0 = 0, p1 = 0, p2 = 0, p3 = 0;
    int v0 = 0, v1 = 0, v2 = 0, v3 = 0;
    if (base < n)     { p0 = physidx(base,     NBtot); v0 = buf[p0]; }
    if (base + 1 < n) { p1 = physidx(base + 1, NBtot); v1 = buf[p1]; }
    if (base + 2 < n) { p2 = physidx(base + 2, NBtot); v2 = buf[p2]; }
    if (base + 3 < n) { p3 = physidx(base + 3, NBtot); v3 = buf[p3]; }
    const int tsum = v0 + v1 + v2 + v3;
    sh[t] = tsum;
    __syncthreads();
    for (int o = 1; o < 1024; o <<= 1) {
        int u = (t >= o) ? sh[t - o] : 0;
        __syncthreads();
        sh[t] += u;
        __syncthreads();
    }
    const int texcl = sh[t] - tsum;
    if (base < n)     buf[p0] = texcl;
    if (base + 1 < n) buf[p1] = texcl + v0;
    if (base + 2 < n) buf[p2] = texcl + v0 + v1;
    if (base + 3 < n) buf[p3] = texcl + v0 + v1 + v2;
    if (t == 1023) partials[blockIdx.x] = sh[t];
}

__global__ __launch_bounds__(1024) void gscan_b_kernel(int* __restrict__ partials,
                                                       int nb)
{
    __shared__ int sh[1024];
    const int t = threadIdx.x;
    int v = (t < nb) ? partials[t] : 0;
    sh[t] = v;
    __syncthreads();
    for (int o = 1; o < 1024; o <<= 1) {
        int u = (t >= o) ? sh[t - o] : 0;
        __syncthreads();
        sh[t] += u;
        __syncthreads();
    }
    if (t < nb) partials[t] = sh[t] - v;   // exclusive
}

__global__ void gscan_c_kernel(int* __restrict__ buf,
                               const int* __restrict__ partials, int n, int NBtot)
{
    int l = blockIdx.x * blockDim.x + threadIdx.x;
    if (l < n) buf[physidx(l, NBtot)] += partials[l >> 12];
}

// ---------------------------------------------------------------------------
// Scatter pass: append (src | dfine<<16) into block-private bucket ranges.
// ---------------------------------------------------------------------------
__global__ __launch_bounds__(1024) void scatter_kernel(
    RelSet rs, const int* __restrict__ O, unsigned* __restrict__ temp, int NBr)
{
    extern __shared__ int cur[];
    const int NBtot = 4 * NBr;
    for (int i = threadIdx.x; i < NBtot; i += 1024)
        cur[i] = O[blockIdx.x * NBtot + i];
    __syncthreads();
    for (int e = blockIdx.x * 1024 + threadIdx.x; e < rs.off4; e += NBLK * 1024) {
        int r, le; const int *s, *d;
        pick(rs, e, r, s, d, le);
        int dd = d[le];
        int b = r * NBr + (dd >> 7);
        int pos = atomicAdd(&cur[b], 1);
        temp[pos] = (unsigned)s[le] | ((unsigned)(dd & 127) << 16);
    }
}

// ---------------------------------------------------------------------------
// Fill: one block per bucket; rowptr + edge placement, all block-local.
// ---------------------------------------------------------------------------
__global__ __launch_bounds__(256) void fillb_kernel(
    RelSet rs, const int* __restrict__ O, const unsigned* __restrict__ temp,
    int* __restrict__ rowptr4, unsigned short* __restrict__ esrc4,
    int NBr, int NP, int EP, int TE)
{
    __shared__ int cnt[128];
    __shared__ int cur[128];
    const int b = blockIdx.x;
    const int NBtot = 4 * NBr;
    const int r = b / NBr;
    const int bloc = b - r * NBr;
    const int dbase = bloc << 7;
    const int nd = ndst_of(rs, r);
    const int bstart = O[b];
    const int bend   = (b + 1 < NBtot) ? O[b + 1] : TE;
    const int relstart = O[r * NBr];
    const int relend   = (r + 1 < 4) ? O[(r + 1) * NBr] : TE;
    const int t = threadIdx.x;

    if (t < 128) cnt[t] = 0;
    __syncthreads();
    for (int i = bstart + t; i < bend; i += 256)
        atomicAdd(&cnt[temp[i] >> 16], 1);
    __syncthreads();
    const int orig = (t < 128) ? cnt[t] : 0;
    for (int o = 1; o < 128; o <<= 1) {
        int add = 0;
        if (t < 128 && t >= o) add = cnt[t - o];
        __syncthreads();
        if (t < 128) cnt[t] += add;
        __syncthreads();
    }
    const int bucket_base = bstart - relstart;
    if (t < 128) {
        const int excl = cnt[t] - orig;
        cur[t] = bucket_base + excl;
        const int d = dbase + t;
        if (d < nd) rowptr4[r * (NP + 1) + d] = bucket_base + excl;
    }
    if (t == 0 && bloc == NBr - 1)
        rowptr4[r * (NP + 1) + nd] = relend - relstart;
    __syncthreads();
    unsigned short* es = esrc4 + (size_t)r * EP;
    for (int i = bstart + t; i < bend; i += 256) {
        unsigned u = temp[i];
        int pos = atomicAdd(&cur[u >> 16], 1);
        es[pos] = (unsigned short)(u & 0xFFFFu);
    }
}

// ---------------------------------------------------------------------------
// pack4: pre-transpose 4 weight matrices into global B-frag order (bf16 bits):
// Wp[((kt*4+ct)*64 + quad*16+n)*8 + j] = bf16(W[kt*32+quad*8+j][ct*16+n])
// ---------------------------------------------------------------------------
__device__ __forceinline__ void pack_one(const void* W, unsigned short* Wp,
                                         int i, bool f32)
{
    int k = i >> 6, c = i & 63;
    int kt = k >> 5, q = (k >> 3) & 3, j = k & 7;
    int ct = c >> 4, n = c & 15;
    Wp[(((kt * 4 + ct) * 64) + q * 16 + n) * 8 + j] = f2bfbits(ldx(W, i, f32));
}

__global__ __launch_bounds__(256) void pack4_kernel(
    const void* __restrict__ W0, const void* __restrict__ W1,
    const void* __restrict__ W2, const void* __restrict__ W3,
    unsigned short* __restrict__ P0, unsigned short* __restrict__ P1,
    unsigned short* __restrict__ P2, unsigned short* __restrict__ P3,
    const int* __restrict__ flag)
{
    const bool f32 = (flag[0] != 0);
    int i = blockIdx.x * 256 + threadIdx.x;
    if (i < 8192)       pack_one(W0, P0, i, f32);
    else if (i < 16384) pack_one(W1, P1, i - 8192, f32);
    else if (i < 24576) pack_one(W2, P2, i - 16384, f32);
    else if (i < 28672) pack_one(W3, P3, i - 24576, f32);
}

// ---------------------------------------------------------------------------
// wvec2: wv1 = W1 @ a1, wv2 = W2 @ a2 (both K=128)
// ---------------------------------------------------------------------------
__global__ void wvec2_kernel(const void* __restrict__ W1, const void* __restrict__ a1,
                             const void* __restrict__ W2, const void* __restrict__ a2,
                             float* __restrict__ wv1, float* __restrict__ wv2,
                             const int* __restrict__ flag)
{
    const bool f32 = (flag[0] != 0);
    const int t = threadIdx.x;
    const void* W = (t < 128) ? W1 : W2;
    const void* a = (t < 128) ? a1 : a2;
    const int k = t & 127;
    float s = 0.f;
    for (int c = 0; c < 64; ++c) s += ldx(W, (size_t)k * 64 + c, f32) * ldx(a, c, f32);
    ((t < 128) ? wv1 : wv2)[k] = s;
}

// ---------------------------------------------------------------------------
// MFMA projection: B-frags loaded straight from packed global W (no LDS).
// ---------------------------------------------------------------------------
struct ProjArg {
    const void* X; const unsigned short* Wp; const void* a1; const void* a2;
    const float* wvx;
    bf16* H; float* al1; float* al2; float* alx;
    int N;
};

template <int K>
__device__ __forceinline__ void proj_body(const ProjArg& P, bool f32,
                                          int bid, int nblocks)
{
    constexpr int NKT = K / 32;
    const int tid = threadIdx.x;
    const int wave = tid >> 6, lane = tid & 63;
    const int quad = lane >> 4, n = lane & 15;

    // B fragments: 16 coalesced 16B global loads (L2-hot), conflict-free
    s16v8 Bf[NKT][4];
    #pragma unroll
    for (int kt = 0; kt < NKT; ++kt)
        #pragma unroll
        for (int ct = 0; ct < 4; ++ct)
            Bf[kt][ct] = *(const s16v8*)&P.Wp[((kt * 4 + ct) * 64 + lane) * 8];

    float a1v[4], a2v[4];
    #pragma unroll
    for (int ct = 0; ct < 4; ++ct) {
        a1v[ct] = P.a1 ? ldx(P.a1, ct * 16 + n, f32) : 0.f;
        a2v[ct] = P.a2 ? ldx(P.a2, ct * 16 + n, f32) : 0.f;
    }
    float wv[NKT][8];
    if (P.wvx) {
        #pragma unroll
        for (int kt = 0; kt < NKT; ++kt)
            #pragma unroll
            for (int j = 0; j < 8; ++j)
                wv[kt][j] = P.wvx[kt * 32 + quad * 8 + j];
    }

    const int tiles = (P.N + 15) / 16;
    for (int tb = bid * 4 + wave; tb < tiles; tb += nblocks * 4) {
        const int r0 = tb * 16;
        const int arow = r0 + n;
        const int ars  = (arow < P.N) ? arow : 0;

        f32v4 acc[4];
        #pragma unroll
        for (int ct = 0; ct < 4; ++ct) acc[ct] = (f32v4){0.f, 0.f, 0.f, 0.f};
        float txd = 0.f;

        #pragma unroll
        for (int kt = 0; kt < NKT; ++kt) {
            s16v8 As;
            if (f32) {
                const float4* xp = (const float4*)P.X +
                    ((size_t)ars * K + kt * 32 + quad * 8) / 4;
                float4 x0 = xp[0], x1 = xp[1];
                As[0] = (short)f2bfbits(x0.x); As[1] = (short)f2bfbits(x0.y);
                As[2] = (short)f2bfbits(x0.z); As[3] = (short)f2bfbits(x0.w);
                As[4] = (short)f2bfbits(x1.x); As[5] = (short)f2bfbits(x1.y);
                As[6] = (short)f2bfbits(x1.z); As[7] = (short)f2bfbits(x1.w);
            } else {
                As = *(const s16v8*)((const unsigned short*)P.X +
                    (size_t)ars * K + kt * 32 + quad * 8);
            }
            if (P.wvx) {
                #pragma unroll
                for (int j = 0; j < 8; ++j)
                    txd = fmaf(bf2f((unsigned short)As[j]), wv[kt][j], txd);
            }
            bf16v8 Ab = __builtin_bit_cast(bf16v8, As);
            #pragma unroll
            for (int ct = 0; ct < 4; ++ct)
                acc[ct] = __builtin_amdgcn_mfma_f32_16x16x32_bf16(
                    Ab, __builtin_bit_cast(bf16v8, Bf[kt][ct]), acc[ct], 0, 0, 0);
        }

        if (P.alx) {
            txd += __shfl_xor(txd, 16);
            txd += __shfl_xor(txd, 32);
            if (lane < 16 && r0 + lane < P.N) P.alx[r0 + lane] = txd;
        }

        #pragma unroll
        for (int i = 0; i < 4; ++i) {
            const int r = r0 + quad * 4 + i;
            const bool rv = (r < P.N);
            if (rv && P.H) {
                #pragma unroll
                for (int ct = 0; ct < 4; ++ct)
                    P.H[(size_t)r * 64 + ct * 16 + n] = __float2bfloat16(acc[ct][i]);
            }
            if (P.al1) {
                float t = acc[0][i] * a1v[0] + acc[1][i] * a1v[1] +
                          acc[2][i] * a1v[2] + acc[3][i] * a1v[3];
                #pragma unroll
                for (int o = 1; o < 16; o <<= 1) t += __shfl_xor(t, o);
                if (rv && n == 0) P.al1[r] = t;
            }
            if (P.al2) {
                float t = acc[0][i] * a2v[0] + acc[1][i] * a2v[1] +
                          acc[2][i] * a2v[2] + acc[3][i] * a2v[3];
                #pragma unroll
                for (int o = 1; o < 16; o <<= 1) t += __shfl_xor(t, o);
                if (rv && n == 0) P.al2[r] = t;
            }
        }
    }
}

template <int KA, int KB, int KC>
__global__ __launch_bounds__(256) void proj3_kernel(ProjArg A, ProjArg B, ProjArg C,
                                                    int nA, int nB,
                                                    const int* __restrict__ flag)
{
    const bool f32 = (flag[0] != 0);
    const int bx = blockIdx.x;
    if (bx < nA)            proj_body<KA>(A, f32, bx, nA);
    else if (bx < nA + nB)  proj_body<KB>(B, f32, bx - nA, nB);
    else                    proj_body<KC>(C, f32, bx - nA - nB,
                                          gridDim.x - nA - nB);
}

template <int K>
__global__ __launch_bounds__(256) void proj1_kernel(ProjArg A,
                                                    const int* __restrict__ flag)
{
    proj_body<K>(A, flag[0] != 0, blockIdx.x, gridDim.x);
}

// ---------------------------------------------------------------------------
// Fused dual-relation softmax aggregation, 2 channels/lane (round-0 proven
// structure). Single change vs round 0: the j-loop is HAND-unrolled 2x
// (8 edges per relation per iteration, 8 independent dword gathers in
// flight per lane vs 4). #pragma unroll was a no-op (identical VGPR/dur).
// Overrun lanes are safe: lane >= nn has s=0,w=0 (weight-0 fma on row 0);
// max shfl index = 56+6+1 = 63.
// ---------------------------------------------------------------------------
__global__ __launch_bounds__(256) void agg2_kernel(
    const int* __restrict__ rp1, const unsigned short* __restrict__ es1,
    const unsigned* __restrict__ HS1, const float* __restrict__ als1,
    const float* __restrict__ ald1,
    const int* __restrict__ rp2, const unsigned short* __restrict__ es2,
    const unsigned* __restrict__ HS2, const float* __restrict__ als2,
    const float* __restrict__ ald2,
    const void* __restrict__ b1, const void* __restrict__ b2,
    void* __restrict__ out, size_t out_off, int n, const int* __restrict__ flag)
{
    const int gw   = (blockIdx.x * blockDim.x + threadIdx.x) >> 6;
    const int lane = threadIdx.x & 63;
    if (gw >= n) return;
    const int half = lane >> 5;      // 0: edge j, 1: edge j+1
    const int ch2  = lane & 31;      // channel pair (2*ch2, 2*ch2+1)

    int p1 = rp1[gw], e1 = rp1[gw + 1];
    int p2 = rp2[gw], e2 = rp2[gw + 1];
    const float ad1 = ald1[gw], ad2 = ald2[gw];

    float l1a = 0.f, h1a = 0.f, l1b = 0.f, h1b = 0.f, den1 = 0.f;
    float l2a = 0.f, h2a = 0.f, l2b = 0.f, h2b = 0.f, den2 = 0.f;

    while (p1 < e1 || p2 < e2) {
        int nn1 = e1 - p1; nn1 = nn1 < 0 ? 0 : (nn1 > 64 ? 64 : nn1);
        int nn2 = e2 - p2; nn2 = nn2 < 0 ? 0 : (nn2 > 64 ? 64 : nn2);
        int s1 = 0, s2 = 0; float w1 = 0.f, w2 = 0.f;
        if (lane < nn1) {
            s1 = es1[p1 + lane];
            float l = als1[s1] + ad1;
            l = (l > 0.f) ? l : 0.2f * l;
            w1 = __expf(l);
        }
        if (lane < nn2) {
            s2 = es2[p2 + lane];
            float l = als2[s2] + ad2;
            l = (l > 0.f) ? l : 0.2f * l;
            w2 = __expf(l);
        }
        den1 += w1; den2 += w2;

        const int jm = (nn1 > nn2) ? nn1 : nn2;
        for (int j = 0; j < jm; j += 8) {
            // 8 edges per relation: all 16 shfl address sources first,
            // then 8 independent gathers, then the fma block.
            int   sA1 = __shfl(s1, j + half),     sB1 = __shfl(s1, j + 2 + half);
            int   sC1 = __shfl(s1, j + 4 + half), sD1 = __shfl(s1, j + 6 + half);
            float wA1 = __shfl(w1, j + half),     wB1 = __shfl(w1, j + 2 + half);
            float wC1 = __shfl(w1, j + 4 + half), wD1 = __shfl(w1, j + 6 + half);
            int   sA2 = __shfl(s2, j + half),     sB2 = __shfl(s2, j + 2 + half);
            int   sC2 = __shfl(s2, j + 4 + half), sD2 = __shfl(s2, j + 6 + half);
            float wA2 = __shfl(w2, j + half),     wB2 = __shfl(w2, j + 2 + half);
            float wC2 = __shfl(w2, j + 4 + half), wD2 = __shfl(w2, j + 6 + half);
            unsigned vA1 = HS1[(size_t)sA1 * 32 + ch2];
            unsigned vB1 = HS1[(size_t)sB1 * 32 + ch2];
            unsigned vC1 = HS1[(size_t)sC1 * 32 + ch2];
            unsigned vD1 = HS1[(size_t)sD1 * 32 + ch2];
            unsigned vA2 = HS2[(size_t)sA2 * 32 + ch2];
            unsigned vB2 = HS2[(size_t)sB2 * 32 + ch2];
            unsigned vC2 = HS2[(size_t)sC2 * 32 + ch2];
            unsigned vD2 = HS2[(size_t)sD2 * 32 + ch2];
            l1a = fmaf(wA1, bflo(vA1), l1a); h1a = fmaf(wA1, bfhi(vA1), h1a);
            l1b = fmaf(wB1, bflo(vB1), l1b); h1b = fmaf(wB1, bfhi(vB1), h1b);
            l1a = fmaf(wC1, bflo(vC1), l1a); h1a = fmaf(wC1, bfhi(vC1), h1a);
            l1b = fmaf(wD1, bflo(vD1), l1b); h1b = fmaf(wD1, bfhi(vD1), h1b);
            l2a = fmaf(wA2, bflo(vA2), l2a); h2a = fmaf(wA2, bfhi(vA2), h2a);
            l2b = fmaf(wB2, bflo(vB2), l2b); h2b = fmaf(wB2, bfhi(vB2), h2b);
            l2a = fmaf(wC2, bflo(vC2), l2a); h2a = fmaf(wC2, bfhi(vC2), h2a);
            l2b = fmaf(wD2, bflo(vD2), l2b); h2b = fmaf(wD2, bfhi(vD2), h2b);
        }
        p1 += nn1; p2 += nn2;
    }

    float lo1 = l1a + l1b, hi1 = h1a + h1b;
    float lo2 = l2a + l2b, hi2 = h2a + h2b;
    lo1 += __shfl_xor(lo1, 32); hi1 += __shfl_xor(hi1, 32);
    lo2 += __shfl_xor(lo2, 32); hi2 += __shfl_xor(hi2, 32);
    den1 = wave_sum(den1);
    den2 = wave_sum(den2);
    const float inv1 = 1.0f / (den1 + 1e-16f);
    const float inv2 = 1.0f / (den2 + 1e-16f);

    if (half == 0) {
        const bool f32 = (flag[0] != 0);
        const int c0 = 2 * ch2;
        float vlo = 0.5f * (lo1 * inv1 + lo2 * inv2 +
                            ldx(b1, c0, f32) + ldx(b2, c0, f32));
        float vhi = 0.5f * (hi1 * inv1 + hi2 * inv2 +
                            ldx(b1, c0 + 1, f32) + ldx(b2, c0 + 1, f32));
        const size_t pairidx = (out_off >> 1) + (size_t)gw * 32 + ch2;
        if (f32) ((float2*)out)[pairidx] = make_float2(vlo, vhi);
        else {
            ushort2 u2 = make_ushort2(f2bfbits(vlo), f2bfbits(vhi));
            ((ushort2*)out)[pairidx] = u2;
        }
    }
}

// ---------------------------------------------------------------------------
extern "C" void kernel_launch(void* const* d_in, const int* in_sizes, int n_in,
                              void* d_out, int out_size, void* d_ws, size_t ws_size,
                              hipStream_t stream)
{
    const void* x_t = d_in[0];
    const void* x_d = d_in[1];
    const int* ei_tt = (const int*)d_in[2];
    const int* ei_dt = (const int*)d_in[3];
    const int* ei_dd = (const int*)d_in[4];
    const int* ei_td = (const int*)d_in[5];
    const void* W_tt     = d_in[6];
    const void* att_tt_s = d_in[7];
    const void* att_tt_d = d_in[8];
    const void* b_tt     = d_in[9];
    const void* W_dt_src = d_in[10];
    const void* W_dt_dst = d_in[11];
    const void* att_dt_s = d_in[12];
    const void* att_dt_d = d_in[13];
    const void* b_dt     = d_in[14];
    const void* W_dd     = d_in[15];
    const void* att_dd_s = d_in[16];
    const void* att_dd_d = d_in[17];
    const void* b_dd     = d_in[18];
    const void* W_td_src = d_in[19];
    const void* W_td_dst = d_in[20];
    const void* att_td_s = d_in[21];
    const void* att_td_d = d_in[22];
    const void* b_td     = d_in[23];

    const int NT = in_sizes[0] / 128;
    const int ND = in_sizes[1] / 128;
    const int Ett = in_sizes[2] / 2, Edt = in_sizes[3] / 2,
              Edd = in_sizes[4] / 2, Etd = in_sizes[5] / 2;
    const int NMAX = (NT > ND) ? NT : ND;
    int EMAX = Ett;
    if (Edt > EMAX) EMAX = Edt;
    if (Edd > EMAX) EMAX = Edd;
    if (Etd > EMAX) EMAX = Etd;
    const int TE = Ett + Edt + Edd + Etd;

    const int NBr  = (NMAX + 127) >> 7;      // buckets per relation
    const int NBtot = 4 * NBr;
    const int HM = NBtot * NBLK;             // histogram matrix size

    // ---- workspace ----
    char* wptr = (char*)d_ws;
    auto alloc = [&](size_t bytes) -> void* {
        void* p = (void*)wptr;
        wptr += (bytes + 255) & ~(size_t)255;
        return p;
    };
    bf16*  h1      = (bf16*)alloc((size_t)NMAX * 64 * 2);
    bf16*  h2      = (bf16*)alloc((size_t)NMAX * 64 * 2);
    float* als[4]; float* ald[4];
    for (int r = 0; r < 4; ++r) {
        als[r] = (float*)alloc((size_t)NMAX * 4);
        ald[r] = (float*)alloc((size_t)NMAX * 4);
    }
    int*   hist    = (int*)alloc((size_t)HM * 4);
    int*   rowptr4 = (int*)alloc((size_t)4 * (NMAX + 1) * 4);
    unsigned short* esrc4 = (unsigned short*)alloc((size_t)4 * EMAX * 2);
    unsigned* temp = (unsigned*)alloc((size_t)TE * 4);
    int*   gpart   = (int*)alloc(1024 * 4);
    float* wvec_dt = (float*)alloc(128 * 4);
    float* wvec_td = (float*)alloc(128 * 4);
    unsigned short* wp_tt = (unsigned short*)alloc(8192 * 2);
    unsigned short* wp_dt = (unsigned short*)alloc(8192 * 2);
    unsigned short* wp_dd = (unsigned short*)alloc(8192 * 2);
    unsigned short* wp_td = (unsigned short*)alloc(4096 * 2);
    int*   flag    = (int*)alloc(256 * 4);
    bf16*  h3      = (bf16*)temp;   // temp dead after fillb; alias for dd's H

    RelSet rs;
    rs.src0 = ei_tt; rs.dst0 = ei_tt + Ett;
    rs.src1 = ei_dt; rs.dst1 = ei_dt + Edt;
    rs.src2 = ei_dd; rs.dst2 = ei_dd + Edd;
    rs.src3 = ei_td; rs.dst3 = ei_td + Etd;
    rs.off1 = Ett; rs.off2 = Ett + Edt; rs.off3 = Ett + Edt + Edd; rs.off4 = TE;
    rs.nd0 = NT; rs.nd1 = NT; rs.nd2 = ND; rs.nd3 = ND;

    detect_kernel<<<1, 256, 0, stream>>>((const unsigned*)x_t, 4096, flag);

    // ---- weight packing + wvecs (tiny) ----
    pack4_kernel<<<112, 256, 0, stream>>>(W_tt, W_dt_src, W_dd, W_td_src,
                                          wp_tt, wp_dt, wp_dd, wp_td, flag);
    wvec2_kernel<<<1, 256, 0, stream>>>(W_dt_dst, att_dt_d, W_td_dst, att_td_d,
                                        wvec_dt, wvec_td, flag);

    // ---- CSR build ----
    const size_t ldsB = (size_t)NBtot * 4;
    pass1_kernel<<<NBLK, 1024, ldsB, stream>>>(rs, hist, NBr);
    const int gnb = (HM + 4095) / 4096;
    gscan_a_kernel<<<gnb, 1024, 0, stream>>>(hist, HM, NBtot, gpart);
    gscan_b_kernel<<<1, 1024, 0, stream>>>(gpart, gnb);
    gscan_c_kernel<<<(HM + 255) / 256, 256, 0, stream>>>(hist, gpart, HM, NBtot);
    scatter_kernel<<<NBLK, 1024, ldsB, stream>>>(rs, hist, temp, NBr);
    fillb_kernel<<<NBtot, 256, 0, stream>>>(rs, hist, temp, rowptr4, esrc4,
                                            NBr, NMAX, EMAX, TE);

    // ---- projections tt -> h1, dt -> h2, dd -> h3 (temp alias) ----
    ProjArg Ptt{ x_t, wp_tt, att_tt_s, att_tt_d, wvec_dt,
                 h1, als[0], ald[0], ald[1], NT };
    ProjArg Pdt{ x_d, wp_dt, att_dt_s, nullptr, wvec_td,
                 h2, als[1], nullptr, ald[3], ND };
    ProjArg Pdd{ x_d, wp_dd, att_dd_s, att_dd_d, nullptr,
                 h3, als[2], ald[2], nullptr, ND };
    proj3_kernel<128, 128, 128><<<2304, 256, 0, stream>>>(Ptt, Pdt, Pdd,
                                                          768, 768, flag);

    // ---- target aggregate (tt rel0 + dt rel1) -> x_target_new ----
    agg2_kernel<<<(NT + 3) / 4, 256, 0, stream>>>(
        rowptr4 + 0 * (NMAX + 1), esrc4 + (size_t)0 * EMAX,
        (const unsigned*)h1, als[0], ald[0],
        rowptr4 + 1 * (NMAX + 1), esrc4 + (size_t)1 * EMAX,
        (const unsigned*)h2, als[1], ald[1],
        b_tt, b_dt, d_out, 0, NT, flag);

    // ---- td projection (reads x_target_new) -> h1 (reused) ----
    ProjArg Ptd{ d_out, wp_td, att_td_s, nullptr, nullptr,
                 h1, als[3], nullptr, nullptr, NT };
    proj1_kernel<64><<<1024, 256, 0, stream>>>(Ptd, flag);

    // ---- drug aggregate (dd rel2 + td rel3) -> x_drug_new ----
    agg2_kernel<<<(ND + 3) / 4, 256, 0, stream>>>(
        rowptr4 + 2 * (NMAX + 1), esrc4 + (size_t)2 * EMAX,
        (const unsigned*)h3, als[2], ald[2],
        rowptr4 + 3 * (NMAX + 1), esrc4 + (size_t)3 * EMAX,
        (const unsigned*)h1, als[3], ald[3],
        b_dd, b_td, d_out, (size_t)NT * 64, ND, flag);
}